// Round 1
// baseline (3375.980 us; speedup 1.0000x reference)
//
#include <hip/hip_runtime.h>

// ---------------------------------------------------------------------------
// SpatialGATEncoder: 4-layer GATv2 on N=100k nodes, E=800k edges, HID=128.
// Round 0: all-f32 correctness baseline.
//   - CSR build (count/scan/place) once per call -> atomic-free aggregation
//   - edge_score: fused  silu(ea@P+b) @ We  + gather + leakyrelu + att-dot
//   - aggregate: per-dst online softmax + msg accum + bias + LN + silu + res
// ---------------------------------------------------------------------------

// ---------------- CSR build ----------------
__global__ __launch_bounds__(256) void count_kernel(const int* __restrict__ dstv,
                                                    int* __restrict__ deg, int E) {
  int e = blockIdx.x * 256 + threadIdx.x;
  if (e < E) atomicAdd(&deg[dstv[e]], 1);
}

__global__ __launch_bounds__(1024) void scan_kernel(const int* __restrict__ deg,
                                                    int* __restrict__ off,
                                                    int* __restrict__ cursor, int n) {
  __shared__ int wsum[16];
  __shared__ int chunk_base;
  int t = threadIdx.x;
  int lane = t & 63, wid = t >> 6;
  if (t == 0) chunk_base = 0;
  __syncthreads();
  for (int start = 0; start < n; start += 1024) {
    int i = start + t;
    int v = (i < n) ? deg[i] : 0;
    int x = v;
    #pragma unroll
    for (int o = 1; o < 64; o <<= 1) {
      int y = __shfl_up(x, o, 64);
      if (lane >= o) x += y;
    }
    if (lane == 63) wsum[wid] = x;
    __syncthreads();
    if (wid == 0) {
      int w = (lane < 16) ? wsum[lane] : 0;
      #pragma unroll
      for (int o = 1; o < 16; o <<= 1) {
        int y = __shfl_up(w, o, 64);
        if (lane >= o) w += y;
      }
      if (lane < 16) wsum[lane] = w;
    }
    __syncthreads();
    int wbase = (wid == 0) ? 0 : wsum[wid - 1];
    int excl = chunk_base + wbase + (x - v);
    if (i < n) { off[i] = excl; cursor[i] = excl; }
    int total = wsum[15];
    __syncthreads();
    if (t == 0) chunk_base += total;
    __syncthreads();
  }
  if (t == 0) off[n] = chunk_base;
}

__global__ __launch_bounds__(256) void place_kernel(const int* __restrict__ srcv,
                                                    const int* __restrict__ dstv,
                                                    int* __restrict__ cursor,
                                                    int* __restrict__ ssrc,
                                                    int* __restrict__ pos, int E) {
  int e = blockIdx.x * 256 + threadIdx.x;
  if (e < E) {
    int p = atomicAdd(&cursor[dstv[e]], 1);
    ssrc[p] = srcv[e];
    pos[e] = p;
  }
}

// ---------------- layer-0 node projection (K = 12) ----------------
__global__ __launch_bounds__(256) void node_proj0_kernel(
    const float* __restrict__ x,
    const float* __restrict__ Wl, const float* __restrict__ bl,
    const float* __restrict__ Wr, const float* __restrict__ br,
    float* __restrict__ xl, float* __restrict__ xr, int N) {
  int idx = blockIdx.x * 256 + threadIdx.x;
  int node = idx >> 7, col = idx & 127;
  if (node >= N) return;
  float al = bl[col], ar = br[col];
  const float* xrow = x + node * 12;
  #pragma unroll
  for (int k = 0; k < 12; ++k) {
    float xv = xrow[k];
    al += xv * Wl[k * 128 + col];
    ar += xv * Wr[k * 128 + col];
  }
  xl[idx] = al;
  xr[idx] = ar;
}

// ---------------- node projection (K = 128): out = h @ W + bias ----------------
// tile: 64 nodes x 64 cols (blockIdx.y = col half), 256 thr, 4x4 per thread.
__global__ __launch_bounds__(256, 2) void node_proj_kernel(
    const float* __restrict__ h, const float* __restrict__ W,
    const float* __restrict__ bias, float* __restrict__ out, int N) {
  __shared__ float A_sh[64 * 128];   // [node][k]
  __shared__ float W_sh[128 * 64];   // [k][col_local]
  int t = threadIdx.x;
  int half = blockIdx.y;
  int nb = blockIdx.x * 64;
  #pragma unroll
  for (int i = 0; i < 8; ++i) {
    int f4i = i * 256 + t;
    int k = f4i >> 4, c4 = f4i & 15;
    *(float4*)(W_sh + k * 64 + c4 * 4) =
        *(const float4*)(W + k * 128 + half * 64 + c4 * 4);
  }
  #pragma unroll
  for (int i = 0; i < 8; ++i) {
    int f4i = i * 256 + t;
    int node = f4i >> 5, k4 = (f4i & 31) * 4;
    int ng = nb + node;
    float4 v = make_float4(0.f, 0.f, 0.f, 0.f);
    if (ng < N) v = *(const float4*)(h + ng * 128 + k4);
    *(float4*)(A_sh + node * 128 + k4) = v;
  }
  __syncthreads();
  int tx = t & 15, ty = t >> 4;
  float acc[4][4];
  #pragma unroll
  for (int i = 0; i < 4; ++i)
    #pragma unroll
    for (int j = 0; j < 4; ++j) acc[i][j] = 0.f;
  for (int k4 = 0; k4 < 128; k4 += 4) {
    float4 av[4], wv[4];
    #pragma unroll
    for (int i = 0; i < 4; ++i) av[i] = *(const float4*)(A_sh + (ty * 4 + i) * 128 + k4);
    #pragma unroll
    for (int c = 0; c < 4; ++c) wv[c] = *(const float4*)(W_sh + (k4 + c) * 64 + tx * 4);
    #pragma unroll
    for (int i = 0; i < 4; ++i) {
      acc[i][0] += av[i].x * wv[0].x; acc[i][1] += av[i].x * wv[0].y;
      acc[i][2] += av[i].x * wv[0].z; acc[i][3] += av[i].x * wv[0].w;
      acc[i][0] += av[i].y * wv[1].x; acc[i][1] += av[i].y * wv[1].y;
      acc[i][2] += av[i].y * wv[1].z; acc[i][3] += av[i].y * wv[1].w;
      acc[i][0] += av[i].z * wv[2].x; acc[i][1] += av[i].z * wv[2].y;
      acc[i][2] += av[i].z * wv[2].z; acc[i][3] += av[i].z * wv[2].w;
      acc[i][0] += av[i].w * wv[3].x; acc[i][1] += av[i].w * wv[3].y;
      acc[i][2] += av[i].w * wv[3].z; acc[i][3] += av[i].w * wv[3].w;
    }
  }
  int col0 = half * 64 + tx * 4;
  const float4 b4 = *(const float4*)(bias + col0);
  #pragma unroll
  for (int i = 0; i < 4; ++i) {
    int ng = nb + ty * 4 + i;
    if (ng < N) {
      float4 o;
      o.x = acc[i][0] + b4.x; o.y = acc[i][1] + b4.y;
      o.z = acc[i][2] + b4.z; o.w = acc[i][3] + b4.w;
      *(float4*)(out + ng * 128 + col0) = o;
    }
  }
}

// ---------------- fused edge-score kernel ----------------
// per tile (64 edges, 64-col half): e = silu(ea@P+b); ee = e@We;
// m = ee + xl[src] + xr[dst]; score[e,h] += sum_d lrelu(m)*att
__global__ __launch_bounds__(256, 2) void edge_score_kernel(
    const float* __restrict__ eattr,  // E x 3
    const float* __restrict__ Pw,     // 3 x 128
    const float* __restrict__ Pb,     // 128
    const float* __restrict__ We,     // 128 x 128
    const float* __restrict__ attw,   // 128 (H*D flattened)
    const float* __restrict__ xl, const float* __restrict__ xr,
    const int* __restrict__ srcv, const int* __restrict__ dstv,
    const int* __restrict__ pos,
    float* __restrict__ scores, int E) {
  __shared__ float A_sh[64 * 128];   // e tile [edge][k]
  __shared__ float W_sh[128 * 64];   // [k][col_local]
  int t = threadIdx.x;
  int half = blockIdx.y;
  int eb = blockIdx.x * 64;
  #pragma unroll
  for (int i = 0; i < 8; ++i) {
    int f4i = i * 256 + t;
    int k = f4i >> 4, c4 = f4i & 15;
    *(float4*)(W_sh + k * 64 + c4 * 4) =
        *(const float4*)(We + k * 128 + half * 64 + c4 * 4);
  }
  {
    int k4 = (t & 31) * 4;
    const float4 p0 = *(const float4*)(Pw + 0 * 128 + k4);
    const float4 p1 = *(const float4*)(Pw + 1 * 128 + k4);
    const float4 p2 = *(const float4*)(Pw + 2 * 128 + k4);
    const float4 pb = *(const float4*)(Pb + k4);
    #pragma unroll
    for (int i = 0; i < 8; ++i) {
      int el = (t >> 5) + i * 8;
      int eg = eb + el;
      float a0 = 0.f, a1 = 0.f, a2 = 0.f;
      if (eg < E) { a0 = eattr[eg * 3]; a1 = eattr[eg * 3 + 1]; a2 = eattr[eg * 3 + 2]; }
      float4 z;
      z.x = a0 * p0.x + a1 * p1.x + a2 * p2.x + pb.x;
      z.y = a0 * p0.y + a1 * p1.y + a2 * p2.y + pb.y;
      z.z = a0 * p0.z + a1 * p1.z + a2 * p2.z + pb.z;
      z.w = a0 * p0.w + a1 * p1.w + a2 * p2.w + pb.w;
      float4 s;
      s.x = z.x / (1.f + __expf(-z.x));
      s.y = z.y / (1.f + __expf(-z.y));
      s.z = z.z / (1.f + __expf(-z.z));
      s.w = z.w / (1.f + __expf(-z.w));
      *(float4*)(A_sh + el * 128 + k4) = s;
    }
  }
  __syncthreads();
  int tx = t & 15, ty = t >> 4;
  float acc[4][4];
  #pragma unroll
  for (int i = 0; i < 4; ++i)
    #pragma unroll
    for (int j = 0; j < 4; ++j) acc[i][j] = 0.f;
  for (int k4 = 0; k4 < 128; k4 += 4) {
    float4 av[4], wv[4];
    #pragma unroll
    for (int i = 0; i < 4; ++i) av[i] = *(const float4*)(A_sh + (ty * 4 + i) * 128 + k4);
    #pragma unroll
    for (int c = 0; c < 4; ++c) wv[c] = *(const float4*)(W_sh + (k4 + c) * 64 + tx * 4);
    #pragma unroll
    for (int i = 0; i < 4; ++i) {
      acc[i][0] += av[i].x * wv[0].x; acc[i][1] += av[i].x * wv[0].y;
      acc[i][2] += av[i].x * wv[0].z; acc[i][3] += av[i].x * wv[0].w;
      acc[i][0] += av[i].y * wv[1].x; acc[i][1] += av[i].y * wv[1].y;
      acc[i][2] += av[i].y * wv[1].z; acc[i][3] += av[i].y * wv[1].w;
      acc[i][0] += av[i].z * wv[2].x; acc[i][1] += av[i].z * wv[2].y;
      acc[i][2] += av[i].z * wv[2].z; acc[i][3] += av[i].z * wv[2].w;
      acc[i][0] += av[i].w * wv[3].x; acc[i][1] += av[i].w * wv[3].y;
      acc[i][2] += av[i].w * wv[3].z; acc[i][3] += av[i].w * wv[3].w;
    }
  }
  // epilogue: gather + leakyrelu + att-dot -> per-(edge,head) partial sums
  int col0 = half * 64 + tx * 4;
  const float4 at4 = *(const float4*)(attw + col0);
  int head = half * 2 + (tx >> 3);
  float psum[4];
  #pragma unroll
  for (int i = 0; i < 4; ++i) {
    int eg = eb + ty * 4 + i;
    int sv = 0, dv = 0;
    if (eg < E) { sv = srcv[eg]; dv = dstv[eg]; }
    const float4 xlv = *(const float4*)(xl + sv * 128 + col0);
    const float4 xrv = *(const float4*)(xr + dv * 128 + col0);
    float m0 = acc[i][0] + xlv.x + xrv.x;
    float m1 = acc[i][1] + xlv.y + xrv.y;
    float m2 = acc[i][2] + xlv.z + xrv.z;
    float m3 = acc[i][3] + xlv.w + xrv.w;
    m0 = (m0 > 0.f) ? m0 : 0.2f * m0;
    m1 = (m1 > 0.f) ? m1 : 0.2f * m1;
    m2 = (m2 > 0.f) ? m2 : 0.2f * m2;
    m3 = (m3 > 0.f) ? m3 : 0.2f * m3;
    psum[i] = m0 * at4.x + m1 * at4.y + m2 * at4.z + m3 * at4.w;
  }
  #pragma unroll
  for (int o = 1; o < 8; o <<= 1) {
    #pragma unroll
    for (int i = 0; i < 4; ++i) psum[i] += __shfl_xor(psum[i], o, 8);
  }
  if ((tx & 7) == 0) {
    #pragma unroll
    for (int i = 0; i < 4; ++i) {
      int eg = eb + ty * 4 + i;
      if (eg < E) scores[pos[eg] * 4 + head] = psum[i];
    }
  }
}

// ---------------- aggregation: online softmax + LN + silu + residual ----------------
// one wave per dst node; lane l owns dims {2l, 2l+1}; head = lane>>4.
__global__ __launch_bounds__(256) void aggregate_kernel(
    const float* __restrict__ xl, const float* __restrict__ scores,
    const int* __restrict__ off, const int* __restrict__ ssrc,
    const float* __restrict__ bias,
    const float* __restrict__ lng, const float* __restrict__ lnb,
    const float* __restrict__ h_in, float* __restrict__ h_out, int N) {
  int wid = threadIdx.x >> 6, lane = threadIdx.x & 63;
  int n = blockIdx.x * 4 + wid;
  if (n >= N) return;
  int hh = lane >> 4;
  int p0 = off[n], p1 = off[n + 1];
  float rm = -3.0e38f, rden = 0.f, a0 = 0.f, a1 = 0.f;
  for (int p = p0; p < p1; ++p) {
    float s = scores[p * 4 + hh];
    int sp = ssrc[p];
    float mn = fmaxf(rm, s);
    float c = __expf(rm - mn);
    float w = __expf(s - mn);
    const float2 xv = *(const float2*)(xl + sp * 128 + lane * 2);
    rden = rden * c + w;
    a0 = a0 * c + w * xv.x;
    a1 = a1 * c + w * xv.y;
    rm = mn;
  }
  float inv = 1.f / (rden + 1e-16f);
  const float2 bb = *(const float2*)(bias + lane * 2);
  float v0 = a0 * inv + bb.x;
  float v1 = a1 * inv + bb.y;
  float s1 = v0 + v1, s2 = v0 * v0 + v1 * v1;
  #pragma unroll
  for (int o = 1; o < 64; o <<= 1) {
    s1 += __shfl_xor(s1, o, 64);
    s2 += __shfl_xor(s2, o, 64);
  }
  float mean = s1 * (1.f / 128.f);
  float var = s2 * (1.f / 128.f) - mean * mean;
  float rs = rsqrtf(var + 1e-5f);
  const float2 g2 = *(const float2*)(lng + lane * 2);
  const float2 b2 = *(const float2*)(lnb + lane * 2);
  float y0 = (v0 - mean) * rs * g2.x + b2.x;
  float y1 = (v1 - mean) * rs * g2.y + b2.y;
  float sy0 = y0 / (1.f + __expf(-y0));
  float sy1 = y1 / (1.f + __expf(-y1));
  float o0 = sy0, o1 = sy1;
  if (h_in) {
    const float2 hv = *(const float2*)(h_in + n * 128 + lane * 2);
    o0 += hv.x; o1 += hv.y;
  }
  float2 ov; ov.x = o0; ov.y = o1;
  *(float2*)(h_out + n * 128 + lane * 2) = ov;
}

// ---------------------------------------------------------------------------
extern "C" void kernel_launch(void* const* d_in, const int* in_sizes, int n_in,
                              void* d_out, int out_size, void* d_ws, size_t ws_size,
                              hipStream_t stream) {
  const float* x       = (const float*)d_in[0];
  const int*   eidx    = (const int*)d_in[1];
  const float* eattr   = (const float*)d_in[2];
  const float* Pw      = (const float*)d_in[3];
  const float* Pb      = (const float*)d_in[4];
  const float* l0_Wl   = (const float*)d_in[5];
  const float* l0_bl   = (const float*)d_in[6];
  const float* l0_Wr   = (const float*)d_in[7];
  const float* l0_br   = (const float*)d_in[8];
  const float* l0_We   = (const float*)d_in[9];
  const float* l0_att  = (const float*)d_in[10];
  const float* l0_bias = (const float*)d_in[11];
  const float* Wl      = (const float*)d_in[12];
  const float* bl      = (const float*)d_in[13];
  const float* Wr      = (const float*)d_in[14];
  const float* br      = (const float*)d_in[15];
  const float* We      = (const float*)d_in[16];
  const float* att     = (const float*)d_in[17];
  const float* bias    = (const float*)d_in[18];
  const float* ln_g    = (const float*)d_in[19];
  const float* ln_b    = (const float*)d_in[20];
  (void)n_in; (void)out_size; (void)ws_size;

  int N = in_sizes[0] / 12;
  int E = in_sizes[2] / 3;
  const int* srcv = eidx;
  const int* dstv = eidx + E;

  char* w = (char*)d_ws;
  float* xl = (float*)w;      w += (size_t)N * 128 * 4;
  float* xr = (float*)w;      w += (size_t)N * 128 * 4;
  float* h  = (float*)w;      w += (size_t)N * 128 * 4;
  float* scores = (float*)w;  w += (size_t)E * 4 * 4;
  int* deg    = (int*)w;      w += (size_t)N * 4;
  int* off    = (int*)w;      w += (size_t)(N + 1) * 4;
  int* cursor = (int*)w;      w += (size_t)N * 4;
  int* pos    = (int*)w;      w += (size_t)E * 4;
  int* ssrc   = (int*)w;      w += (size_t)E * 4;

  hipMemsetAsync(deg, 0, (size_t)N * 4, stream);
  int gE = (E + 255) / 256;
  count_kernel<<<gE, 256, 0, stream>>>(dstv, deg, E);
  scan_kernel<<<1, 1024, 0, stream>>>(deg, off, cursor, N);
  place_kernel<<<gE, 256, 0, stream>>>(srcv, dstv, cursor, ssrc, pos, E);

  dim3 egrid((E + 63) / 64, 2);
  dim3 ngrid((N + 63) / 64, 2);
  int agrid = (N + 3) / 4;

  // layer 0 (input dim 12, no residual)
  node_proj0_kernel<<<(N * 128 + 255) / 256, 256, 0, stream>>>(
      x, l0_Wl, l0_bl, l0_Wr, l0_br, xl, xr, N);
  edge_score_kernel<<<egrid, 256, 0, stream>>>(
      eattr, Pw, Pb, l0_We, l0_att, xl, xr, srcv, dstv, pos, scores, E);
  aggregate_kernel<<<agrid, 256, 0, stream>>>(
      xl, scores, off, ssrc, l0_bias, ln_g, ln_b, nullptr, h, N);

  // layers 1..3 (residual)
  for (int i = 0; i < 3; ++i) {
    node_proj_kernel<<<ngrid, 256, 0, stream>>>(h, Wl + i * 16384, bl + i * 128, xl, N);
    node_proj_kernel<<<ngrid, 256, 0, stream>>>(h, Wr + i * 16384, br + i * 128, xr, N);
    edge_score_kernel<<<egrid, 256, 0, stream>>>(
        eattr, Pw, Pb, We + i * 16384, att + i * 128, xl, xr, srcv, dstv, pos, scores, E);
    float* hout = (i == 2) ? (float*)d_out : h;
    aggregate_kernel<<<agrid, 256, 0, stream>>>(
        xl, scores, off, ssrc, bias + i * 128,
        ln_g + (i + 1) * 128, ln_b + (i + 1) * 128, h, hout, N);
  }
}

// Round 2
// 2186.444 us; speedup vs baseline: 1.5441x; 1.5441x over previous
//
#include <hip/hip_runtime.h>
#include <hip/hip_bf16.h>

// ---------------------------------------------------------------------------
// SpatialGATEncoder: 4-layer GATv2, N=100k, E=800k, HID=128, H=4, D=32.
// Round 1: edge_score GEMM (silu(ea@P+b) @ We) moved to bf16 MFMA
//          (f32 accumulate). Everything else unchanged from round 0.
// ---------------------------------------------------------------------------

using bf16x8 = __attribute__((ext_vector_type(8))) short;
using f32x4  = __attribute__((ext_vector_type(4))) float;

__device__ inline unsigned short f2bf(float x) {
  __hip_bfloat16 h = __float2bfloat16(x);
  return *reinterpret_cast<unsigned short*>(&h);
}

// ---------------- CSR build ----------------
__global__ __launch_bounds__(256) void count_kernel(const int* __restrict__ dstv,
                                                    int* __restrict__ deg, int E) {
  int e = blockIdx.x * 256 + threadIdx.x;
  if (e < E) atomicAdd(&deg[dstv[e]], 1);
}

__global__ __launch_bounds__(1024) void scan_kernel(const int* __restrict__ deg,
                                                    int* __restrict__ off,
                                                    int* __restrict__ cursor, int n) {
  __shared__ int wsum[16];
  __shared__ int chunk_base;
  int t = threadIdx.x;
  int lane = t & 63, wid = t >> 6;
  if (t == 0) chunk_base = 0;
  __syncthreads();
  for (int start = 0; start < n; start += 1024) {
    int i = start + t;
    int v = (i < n) ? deg[i] : 0;
    int x = v;
    #pragma unroll
    for (int o = 1; o < 64; o <<= 1) {
      int y = __shfl_up(x, o, 64);
      if (lane >= o) x += y;
    }
    if (lane == 63) wsum[wid] = x;
    __syncthreads();
    if (wid == 0) {
      int w = (lane < 16) ? wsum[lane] : 0;
      #pragma unroll
      for (int o = 1; o < 16; o <<= 1) {
        int y = __shfl_up(w, o, 64);
        if (lane >= o) w += y;
      }
      if (lane < 16) wsum[lane] = w;
    }
    __syncthreads();
    int wbase = (wid == 0) ? 0 : wsum[wid - 1];
    int excl = chunk_base + wbase + (x - v);
    if (i < n) { off[i] = excl; cursor[i] = excl; }
    int total = wsum[15];
    __syncthreads();
    if (t == 0) chunk_base += total;
    __syncthreads();
  }
  if (t == 0) off[n] = chunk_base;
}

__global__ __launch_bounds__(256) void place_kernel(const int* __restrict__ srcv,
                                                    const int* __restrict__ dstv,
                                                    int* __restrict__ cursor,
                                                    int* __restrict__ ssrc,
                                                    int* __restrict__ pos, int E) {
  int e = blockIdx.x * 256 + threadIdx.x;
  if (e < E) {
    int p = atomicAdd(&cursor[dstv[e]], 1);
    ssrc[p] = srcv[e];
    pos[e] = p;
  }
}

// ---------------- layer-0 node projection (K = 12) ----------------
__global__ __launch_bounds__(256) void node_proj0_kernel(
    const float* __restrict__ x,
    const float* __restrict__ Wl, const float* __restrict__ bl,
    const float* __restrict__ Wr, const float* __restrict__ br,
    float* __restrict__ xl, float* __restrict__ xr, int N) {
  int idx = blockIdx.x * 256 + threadIdx.x;
  int node = idx >> 7, col = idx & 127;
  if (node >= N) return;
  float al = bl[col], ar = br[col];
  const float* xrow = x + node * 12;
  #pragma unroll
  for (int k = 0; k < 12; ++k) {
    float xv = xrow[k];
    al += xv * Wl[k * 128 + col];
    ar += xv * Wr[k * 128 + col];
  }
  xl[idx] = al;
  xr[idx] = ar;
}

// ---------------- node projection (K = 128): out = h @ W + bias ----------------
__global__ __launch_bounds__(256, 2) void node_proj_kernel(
    const float* __restrict__ h, const float* __restrict__ W,
    const float* __restrict__ bias, float* __restrict__ out, int N) {
  __shared__ float A_sh[64 * 128];
  __shared__ float W_sh[128 * 64];
  int t = threadIdx.x;
  int half = blockIdx.y;
  int nb = blockIdx.x * 64;
  #pragma unroll
  for (int i = 0; i < 8; ++i) {
    int f4i = i * 256 + t;
    int k = f4i >> 4, c4 = f4i & 15;
    *(float4*)(W_sh + k * 64 + c4 * 4) =
        *(const float4*)(W + k * 128 + half * 64 + c4 * 4);
  }
  #pragma unroll
  for (int i = 0; i < 8; ++i) {
    int f4i = i * 256 + t;
    int node = f4i >> 5, k4 = (f4i & 31) * 4;
    int ng = nb + node;
    float4 v = make_float4(0.f, 0.f, 0.f, 0.f);
    if (ng < N) v = *(const float4*)(h + ng * 128 + k4);
    *(float4*)(A_sh + node * 128 + k4) = v;
  }
  __syncthreads();
  int tx = t & 15, ty = t >> 4;
  float acc[4][4];
  #pragma unroll
  for (int i = 0; i < 4; ++i)
    #pragma unroll
    for (int j = 0; j < 4; ++j) acc[i][j] = 0.f;
  for (int k4 = 0; k4 < 128; k4 += 4) {
    float4 av[4], wv[4];
    #pragma unroll
    for (int i = 0; i < 4; ++i) av[i] = *(const float4*)(A_sh + (ty * 4 + i) * 128 + k4);
    #pragma unroll
    for (int c = 0; c < 4; ++c) wv[c] = *(const float4*)(W_sh + (k4 + c) * 64 + tx * 4);
    #pragma unroll
    for (int i = 0; i < 4; ++i) {
      acc[i][0] += av[i].x * wv[0].x; acc[i][1] += av[i].x * wv[0].y;
      acc[i][2] += av[i].x * wv[0].z; acc[i][3] += av[i].x * wv[0].w;
      acc[i][0] += av[i].y * wv[1].x; acc[i][1] += av[i].y * wv[1].y;
      acc[i][2] += av[i].y * wv[1].z; acc[i][3] += av[i].y * wv[1].w;
      acc[i][0] += av[i].z * wv[2].x; acc[i][1] += av[i].z * wv[2].y;
      acc[i][2] += av[i].z * wv[2].z; acc[i][3] += av[i].z * wv[2].w;
      acc[i][0] += av[i].w * wv[3].x; acc[i][1] += av[i].w * wv[3].y;
      acc[i][2] += av[i].w * wv[3].z; acc[i][3] += av[i].w * wv[3].w;
    }
  }
  int col0 = half * 64 + tx * 4;
  const float4 b4 = *(const float4*)(bias + col0);
  #pragma unroll
  for (int i = 0; i < 4; ++i) {
    int ng = nb + ty * 4 + i;
    if (ng < N) {
      float4 o;
      o.x = acc[i][0] + b4.x; o.y = acc[i][1] + b4.y;
      o.z = acc[i][2] + b4.z; o.w = acc[i][3] + b4.w;
      *(float4*)(out + ng * 128 + col0) = o;
    }
  }
}

// ---------------- fused edge-score kernel (bf16 MFMA GEMM core) ----------------
// Block: 64 edges x 128 cols, 256 threads (4 waves), wave w owns edges
// [16w,16w+16). A = silu(ea@P+b) -> bf16 LDS [64][136]; B = We^T bf16 LDS
// [128][136]. 32x mfma_f32_16x16x32_bf16 per wave; f32 epilogue with
// xl/xr gathers + leakyrelu + att-dot + per-head quad reduction.
__global__ __launch_bounds__(256) void edge_score_kernel(
    const float* __restrict__ eattr,  // E x 3
    const float* __restrict__ Pw,     // 3 x 128
    const float* __restrict__ Pb,     // 128
    const float* __restrict__ We,     // 128 x 128
    const float* __restrict__ attw,   // 128 (H*D flattened)
    const float* __restrict__ xl, const float* __restrict__ xr,
    const int* __restrict__ srcv, const int* __restrict__ dstv,
    const int* __restrict__ pos,
    float* __restrict__ scores, int E) {
  __shared__ unsigned short A_sh[64 * 136];    // [edge][k], pad 8
  __shared__ unsigned short Bt_sh[128 * 136];  // [n][k],    pad 8
  int t = threadIdx.x;
  int eb = blockIdx.x * 64;

  // ---- stage B^T = We transposed, f32 -> bf16 ----
  #pragma unroll
  for (int i = 0; i < 16; ++i) {
    int f4i = i * 256 + t;           // 4096 float4 groups
    int k = f4i >> 5;                // row of We (k dim)
    int n0 = (f4i & 31) * 4;         // col group
    const float4 v = *(const float4*)(We + k * 128 + n0);
    Bt_sh[(n0 + 0) * 136 + k] = f2bf(v.x);
    Bt_sh[(n0 + 1) * 136 + k] = f2bf(v.y);
    Bt_sh[(n0 + 2) * 136 + k] = f2bf(v.z);
    Bt_sh[(n0 + 3) * 136 + k] = f2bf(v.w);
  }

  // ---- stage A = silu(ea@P + b), f32 -> bf16 ----
  {
    int k4 = (t & 31) * 4;
    const float4 p0 = *(const float4*)(Pw + 0 * 128 + k4);
    const float4 p1 = *(const float4*)(Pw + 1 * 128 + k4);
    const float4 p2 = *(const float4*)(Pw + 2 * 128 + k4);
    const float4 pb = *(const float4*)(Pb + k4);
    #pragma unroll
    for (int i = 0; i < 8; ++i) {
      int el = (t >> 5) + i * 8;
      int eg = eb + el;
      float a0 = 0.f, a1 = 0.f, a2 = 0.f;
      if (eg < E) { a0 = eattr[eg * 3]; a1 = eattr[eg * 3 + 1]; a2 = eattr[eg * 3 + 2]; }
      float zx = a0 * p0.x + a1 * p1.x + a2 * p2.x + pb.x;
      float zy = a0 * p0.y + a1 * p1.y + a2 * p2.y + pb.y;
      float zz = a0 * p0.z + a1 * p1.z + a2 * p2.z + pb.z;
      float zw = a0 * p0.w + a1 * p1.w + a2 * p2.w + pb.w;
      ushort4 s;
      s.x = f2bf(zx / (1.f + __expf(-zx)));
      s.y = f2bf(zy / (1.f + __expf(-zy)));
      s.z = f2bf(zz / (1.f + __expf(-zz)));
      s.w = f2bf(zw / (1.f + __expf(-zw)));
      *(ushort4*)(A_sh + el * 136 + k4) = s;
    }
  }
  __syncthreads();

  // ---- MFMA: 16 edges x 8 col-tiles per wave, K=128 in 4 steps ----
  int lane = t & 63, wave = t >> 6;
  int m = lane & 15, quad = lane >> 4;
  f32x4 acc[8];
  #pragma unroll
  for (int tt = 0; tt < 8; ++tt)
    #pragma unroll
    for (int r = 0; r < 4; ++r) acc[tt][r] = 0.f;
  #pragma unroll
  for (int s = 0; s < 4; ++s) {
    int k0 = s * 32 + quad * 8;
    bf16x8 a = *(const bf16x8*)(A_sh + (wave * 16 + m) * 136 + k0);
    #pragma unroll
    for (int tt = 0; tt < 8; ++tt) {
      bf16x8 b = *(const bf16x8*)(Bt_sh + (tt * 16 + m) * 136 + k0);
      acc[tt] = __builtin_amdgcn_mfma_f32_16x16x32_bf16(a, b, acc[tt], 0, 0, 0);
    }
  }

  // ---- epilogue: gather + leakyrelu + att-dot + quad reduce ----
  // C layout: for tile tt, element (row = quad*4 + r, col = tt*16 + m) = acc[tt][r]
  int ebase = eb + wave * 16 + quad * 4;
  int sv[4], dv[4], ps[4];
  #pragma unroll
  for (int r = 0; r < 4; ++r) {
    int eg = ebase + r;
    if (eg < E) { sv[r] = srcv[eg]; dv[r] = dstv[eg]; ps[r] = pos[eg]; }
    else { sv[r] = 0; dv[r] = 0; ps[r] = -1; }
  }
  #pragma unroll
  for (int h = 0; h < 4; ++h) {
    int c0 = h * 32 + m;
    int c1 = c0 + 16;
    float at0 = attw[c0], at1 = attw[c1];
    float psum[4];
    #pragma unroll
    for (int r = 0; r < 4; ++r) {
      float m0 = acc[2 * h][r]     + xl[sv[r] * 128 + c0] + xr[dv[r] * 128 + c0];
      float m1 = acc[2 * h + 1][r] + xl[sv[r] * 128 + c1] + xr[dv[r] * 128 + c1];
      m0 = (m0 > 0.f) ? m0 : 0.2f * m0;
      m1 = (m1 > 0.f) ? m1 : 0.2f * m1;
      psum[r] = m0 * at0 + m1 * at1;
    }
    #pragma unroll
    for (int o = 1; o < 16; o <<= 1) {
      #pragma unroll
      for (int r = 0; r < 4; ++r) psum[r] += __shfl_xor(psum[r], o, 16);
    }
    if (m == 0) {
      #pragma unroll
      for (int r = 0; r < 4; ++r)
        if (ps[r] >= 0) scores[ps[r] * 4 + h] = psum[r];
    }
  }
}

// ---------------- aggregation: online softmax + LN + silu + residual ----------------
__global__ __launch_bounds__(256) void aggregate_kernel(
    const float* __restrict__ xl, const float* __restrict__ scores,
    const int* __restrict__ off, const int* __restrict__ ssrc,
    const float* __restrict__ bias,
    const float* __restrict__ lng, const float* __restrict__ lnb,
    const float* __restrict__ h_in, float* __restrict__ h_out, int N) {
  int wid = threadIdx.x >> 6, lane = threadIdx.x & 63;
  int n = blockIdx.x * 4 + wid;
  if (n >= N) return;
  int hh = lane >> 4;
  int p0 = off[n], p1 = off[n + 1];
  float rm = -3.0e38f, rden = 0.f, a0 = 0.f, a1 = 0.f;
  for (int p = p0; p < p1; ++p) {
    float s = scores[p * 4 + hh];
    int sp = ssrc[p];
    float mn = fmaxf(rm, s);
    float c = __expf(rm - mn);
    float w = __expf(s - mn);
    const float2 xv = *(const float2*)(xl + sp * 128 + lane * 2);
    rden = rden * c + w;
    a0 = a0 * c + w * xv.x;
    a1 = a1 * c + w * xv.y;
    rm = mn;
  }
  float inv = 1.f / (rden + 1e-16f);
  const float2 bb = *(const float2*)(bias + lane * 2);
  float v0 = a0 * inv + bb.x;
  float v1 = a1 * inv + bb.y;
  float s1 = v0 + v1, s2 = v0 * v0 + v1 * v1;
  #pragma unroll
  for (int o = 1; o < 64; o <<= 1) {
    s1 += __shfl_xor(s1, o, 64);
    s2 += __shfl_xor(s2, o, 64);
  }
  float mean = s1 * (1.f / 128.f);
  float var = s2 * (1.f / 128.f) - mean * mean;
  float rs = rsqrtf(var + 1e-5f);
  const float2 g2 = *(const float2*)(lng + lane * 2);
  const float2 b2 = *(const float2*)(lnb + lane * 2);
  float y0 = (v0 - mean) * rs * g2.x + b2.x;
  float y1 = (v1 - mean) * rs * g2.y + b2.y;
  float sy0 = y0 / (1.f + __expf(-y0));
  float sy1 = y1 / (1.f + __expf(-y1));
  float o0 = sy0, o1 = sy1;
  if (h_in) {
    const float2 hv = *(const float2*)(h_in + n * 128 + lane * 2);
    o0 += hv.x; o1 += hv.y;
  }
  float2 ov; ov.x = o0; ov.y = o1;
  *(float2*)(h_out + n * 128 + lane * 2) = ov;
}

// ---------------------------------------------------------------------------
extern "C" void kernel_launch(void* const* d_in, const int* in_sizes, int n_in,
                              void* d_out, int out_size, void* d_ws, size_t ws_size,
                              hipStream_t stream) {
  const float* x       = (const float*)d_in[0];
  const int*   eidx    = (const int*)d_in[1];
  const float* eattr   = (const float*)d_in[2];
  const float* Pw      = (const float*)d_in[3];
  const float* Pb      = (const float*)d_in[4];
  const float* l0_Wl   = (const float*)d_in[5];
  const float* l0_bl   = (const float*)d_in[6];
  const float* l0_Wr   = (const float*)d_in[7];
  const float* l0_br   = (const float*)d_in[8];
  const float* l0_We   = (const float*)d_in[9];
  const float* l0_att  = (const float*)d_in[10];
  const float* l0_bias = (const float*)d_in[11];
  const float* Wl      = (const float*)d_in[12];
  const float* bl      = (const float*)d_in[13];
  const float* Wr      = (const float*)d_in[14];
  const float* br      = (const float*)d_in[15];
  const float* We      = (const float*)d_in[16];
  const float* att     = (const float*)d_in[17];
  const float* bias    = (const float*)d_in[18];
  const float* ln_g    = (const float*)d_in[19];
  const float* ln_b    = (const float*)d_in[20];
  (void)n_in; (void)out_size; (void)ws_size;

  int N = in_sizes[0] / 12;
  int E = in_sizes[2] / 3;
  const int* srcv = eidx;
  const int* dstv = eidx + E;

  char* w = (char*)d_ws;
  float* xl = (float*)w;      w += (size_t)N * 128 * 4;
  float* xr = (float*)w;      w += (size_t)N * 128 * 4;
  float* h  = (float*)w;      w += (size_t)N * 128 * 4;
  float* scores = (float*)w;  w += (size_t)E * 4 * 4;
  int* deg    = (int*)w;      w += (size_t)N * 4;
  int* off    = (int*)w;      w += (size_t)(N + 1) * 4;
  int* cursor = (int*)w;      w += (size_t)N * 4;
  int* pos    = (int*)w;      w += (size_t)E * 4;
  int* ssrc   = (int*)w;      w += (size_t)E * 4;

  hipMemsetAsync(deg, 0, (size_t)N * 4, stream);
  int gE = (E + 255) / 256;
  count_kernel<<<gE, 256, 0, stream>>>(dstv, deg, E);
  scan_kernel<<<1, 1024, 0, stream>>>(deg, off, cursor, N);
  place_kernel<<<gE, 256, 0, stream>>>(srcv, dstv, cursor, ssrc, pos, E);

  dim3 egrid((E + 63) / 64);
  dim3 ngrid((N + 63) / 64, 2);
  int agrid = (N + 3) / 4;

  // layer 0 (input dim 12, no residual)
  node_proj0_kernel<<<(N * 128 + 255) / 256, 256, 0, stream>>>(
      x, l0_Wl, l0_bl, l0_Wr, l0_br, xl, xr, N);
  edge_score_kernel<<<egrid, 256, 0, stream>>>(
      eattr, Pw, Pb, l0_We, l0_att, xl, xr, srcv, dstv, pos, scores, E);
  aggregate_kernel<<<agrid, 256, 0, stream>>>(
      xl, scores, off, ssrc, l0_bias, ln_g, ln_b, nullptr, h, N);

  // layers 1..3 (residual)
  for (int i = 0; i < 3; ++i) {
    node_proj_kernel<<<ngrid, 256, 0, stream>>>(h, Wl + i * 16384, bl + i * 128, xl, N);
    node_proj_kernel<<<ngrid, 256, 0, stream>>>(h, Wr + i * 16384, br + i * 128, xr, N);
    edge_score_kernel<<<egrid, 256, 0, stream>>>(
        eattr, Pw, Pb, We + i * 16384, att + i * 128, xl, xr, srcv, dstv, pos, scores, E);
    float* hout = (i == 2) ? (float*)d_out : h;
    aggregate_kernel<<<agrid, 256, 0, stream>>>(
        xl, scores, off, ssrc, bias + i * 128,
        ln_g + (i + 1) * 128, ln_b + (i + 1) * 128, h, hout, N);
  }
}

// Round 3
// 2016.464 us; speedup vs baseline: 1.6742x; 1.0843x over previous
//
#include <hip/hip_runtime.h>
#include <hip/hip_bf16.h>

// ---------------------------------------------------------------------------
// SpatialGATEncoder: 4-layer GATv2, N=100k, E=800k, HID=128, H=4, D=32.
// Round 3:
//  - edge_score: NO LDS. A-frags (silu edge proj) computed in registers;
//    B-frags read from pre-transposed bf16 We^T in global (L1-resident).
//  - edges processed in dst-sorted order (sdst/seattr built in place_kernel):
//    coalesced score writes, L1-local xr gathers.
//  - xl/xr/h_bf stored bf16 only; node projections are MFMA (dual Wl/Wr).
// ---------------------------------------------------------------------------

using bf16x8 = __attribute__((ext_vector_type(8))) short;
using f32x4  = __attribute__((ext_vector_type(4))) float;

__device__ inline unsigned short f2bf(float x) {
  __hip_bfloat16 h = __float2bfloat16(x);
  return *reinterpret_cast<unsigned short*>(&h);
}
__device__ inline float bf2f(unsigned short u) {
  unsigned int x = ((unsigned int)u) << 16;
  return __uint_as_float(x);
}

// ---------------- CSR build ----------------
__global__ __launch_bounds__(256) void count_kernel(const int* __restrict__ dstv,
                                                    int* __restrict__ deg, int E) {
  int e = blockIdx.x * 256 + threadIdx.x;
  if (e < E) atomicAdd(&deg[dstv[e]], 1);
}

__global__ __launch_bounds__(1024) void scan_kernel(const int* __restrict__ deg,
                                                    int* __restrict__ off,
                                                    int* __restrict__ cursor, int n) {
  __shared__ int wsum[16];
  __shared__ int chunk_base;
  int t = threadIdx.x;
  int lane = t & 63, wid = t >> 6;
  if (t == 0) chunk_base = 0;
  __syncthreads();
  for (int start = 0; start < n; start += 1024) {
    int i = start + t;
    int v = (i < n) ? deg[i] : 0;
    int x = v;
    #pragma unroll
    for (int o = 1; o < 64; o <<= 1) {
      int y = __shfl_up(x, o, 64);
      if (lane >= o) x += y;
    }
    if (lane == 63) wsum[wid] = x;
    __syncthreads();
    if (wid == 0) {
      int w = (lane < 16) ? wsum[lane] : 0;
      #pragma unroll
      for (int o = 1; o < 16; o <<= 1) {
        int y = __shfl_up(w, o, 64);
        if (lane >= o) w += y;
      }
      if (lane < 16) wsum[lane] = w;
    }
    __syncthreads();
    int wbase = (wid == 0) ? 0 : wsum[wid - 1];
    int excl = chunk_base + wbase + (x - v);
    if (i < n) { off[i] = excl; cursor[i] = excl; }
    int total = wsum[15];
    __syncthreads();
    if (t == 0) chunk_base += total;
    __syncthreads();
  }
  if (t == 0) off[n] = chunk_base;
}

// sort edges by dst: ssrc/sdst/seattr in segment order
__global__ __launch_bounds__(256) void place_kernel(const int* __restrict__ srcv,
                                                    const int* __restrict__ dstv,
                                                    const float* __restrict__ eattr,
                                                    int* __restrict__ cursor,
                                                    int* __restrict__ ssrc,
                                                    int* __restrict__ sdst,
                                                    float* __restrict__ seattr, int E) {
  int e = blockIdx.x * 256 + threadIdx.x;
  if (e < E) {
    int d = dstv[e];
    int p = atomicAdd(&cursor[d], 1);
    ssrc[p] = srcv[e];
    sdst[p] = d;
    seattr[p * 3 + 0] = eattr[e * 3 + 0];
    seattr[p * 3 + 1] = eattr[e * 3 + 1];
    seattr[p * 3 + 2] = eattr[e * 3 + 2];
  }
}

// ---------------- weight transpose f32 -> bf16, WT[n][k] = W[k][n] ----------------
// 10 blocks: 0..3 We (l0 + 3), 4..6 Wl, 7..9 Wr
__global__ __launch_bounds__(256) void wt_kernel(
    const float* __restrict__ l0_We, const float* __restrict__ We,
    const float* __restrict__ Wl, const float* __restrict__ Wr,
    unsigned short* __restrict__ WeT, unsigned short* __restrict__ WlT,
    unsigned short* __restrict__ WrT) {
  int b = blockIdx.x, t = threadIdx.x;
  const float* src;
  unsigned short* dst;
  if (b == 0)      { src = l0_We;              dst = WeT; }
  else if (b < 4)  { src = We + (b - 1) * 16384; dst = WeT + b * 16384; }
  else if (b < 7)  { src = Wl + (b - 4) * 16384; dst = WlT + (b - 4) * 16384; }
  else             { src = Wr + (b - 7) * 16384; dst = WrT + (b - 7) * 16384; }
  int n = t >> 1, k0 = (t & 1) * 64;
  #pragma unroll
  for (int k = 0; k < 64; ++k)
    dst[n * 128 + k0 + k] = f2bf(src[(k0 + k) * 128 + n]);
}

// ---------------- layer-0 node projection (K = 12) -> bf16 ----------------
__global__ __launch_bounds__(256) void node_proj0_kernel(
    const float* __restrict__ x,
    const float* __restrict__ Wl, const float* __restrict__ bl,
    const float* __restrict__ Wr, const float* __restrict__ br,
    unsigned short* __restrict__ xl, unsigned short* __restrict__ xr, int N) {
  int idx = blockIdx.x * 256 + threadIdx.x;
  int node = idx >> 7, col = idx & 127;
  if (node >= N) return;
  float al = bl[col], ar = br[col];
  const float* xrow = x + node * 12;
  #pragma unroll
  for (int k = 0; k < 12; ++k) {
    float xv = xrow[k];
    al += xv * Wl[k * 128 + col];
    ar += xv * Wr[k * 128 + col];
  }
  xl[idx] = f2bf(al);
  xr[idx] = f2bf(ar);
}

// ---------------- node projection MFMA: xl = h@Wl+bl, xr = h@Wr+br (bf16) ----------------
// block = 64 rows, 4 waves x 16 rows x 128 cols
__global__ __launch_bounds__(256) void node_proj_kernel(
    const unsigned short* __restrict__ hbf,
    const unsigned short* __restrict__ WlT, const float* __restrict__ bl,
    const unsigned short* __restrict__ WrT, const float* __restrict__ br,
    unsigned short* __restrict__ xl, unsigned short* __restrict__ xr, int N) {
  __shared__ unsigned short A_sh[64 * 136];
  int t = threadIdx.x;
  int nb = blockIdx.x * 64;
  #pragma unroll
  for (int it = 0; it < 4; ++it) {
    int idx = it * 256 + t;
    int row = idx >> 4, chunk = idx & 15;
    int ng = nb + row;
    float4 v = make_float4(0.f, 0.f, 0.f, 0.f);
    if (ng < N) v = *(const float4*)(hbf + ng * 128 + chunk * 8);
    *(float4*)(A_sh + row * 136 + chunk * 8) = v;
  }
  __syncthreads();
  int lane = t & 63, w = t >> 6;
  int m = lane & 15, quad = lane >> 4;
  bf16x8 afr[4];
  #pragma unroll
  for (int s = 0; s < 4; ++s)
    afr[s] = *(const bf16x8*)(A_sh + (w * 16 + m) * 136 + s * 32 + quad * 8);
  #pragma unroll
  for (int part = 0; part < 2; ++part) {
    const unsigned short* Bt = part ? WrT : WlT;
    const float* bias = part ? br : bl;
    unsigned short* out = part ? xr : xl;
    f32x4 acc[8];
    #pragma unroll
    for (int tt = 0; tt < 8; ++tt)
      #pragma unroll
      for (int r = 0; r < 4; ++r) acc[tt][r] = 0.f;
    #pragma unroll
    for (int tt = 0; tt < 8; ++tt)
      #pragma unroll
      for (int s = 0; s < 4; ++s) {
        bf16x8 b = *(const bf16x8*)(Bt + (tt * 16 + m) * 128 + s * 32 + quad * 8);
        acc[tt] = __builtin_amdgcn_mfma_f32_16x16x32_bf16(afr[s], b, acc[tt], 0, 0, 0);
      }
    #pragma unroll
    for (int tt = 0; tt < 8; ++tt) {
      int col = tt * 16 + m;
      float bv = bias[col];
      #pragma unroll
      for (int r = 0; r < 4; ++r) {
        int ng = nb + w * 16 + quad * 4 + r;
        if (ng < N) out[ng * 128 + col] = f2bf(acc[tt][r] + bv);
      }
    }
  }
}

// ---------------- fused edge-score kernel (no LDS) ----------------
// block = 64 sorted edges, 4 waves x 16 edges x 128 cols.
__global__ __launch_bounds__(256) void edge_score_kernel(
    const float* __restrict__ seattr,  // E x 3 (sorted)
    const float* __restrict__ Pw,      // 3 x 128
    const float* __restrict__ Pb,      // 128
    const unsigned short* __restrict__ WeT,  // 128 x 128 bf16 [n][k]
    const float* __restrict__ attw,    // 128
    const unsigned short* __restrict__ xl, const unsigned short* __restrict__ xr,
    const int* __restrict__ ssrc, const int* __restrict__ sdst,
    float* __restrict__ scores, int E) {
  int t = threadIdx.x;
  int eb = blockIdx.x * 64;
  int lane = t & 63, w = t >> 6;
  int m = lane & 15, quad = lane >> 4;

  // A-fragment in registers: edge e = eb + w*16 + m, cols k0..k0+7
  int e = eb + w * 16 + m;
  float ea0 = 0.f, ea1 = 0.f, ea2 = 0.f;
  if (e < E) { ea0 = seattr[e * 3]; ea1 = seattr[e * 3 + 1]; ea2 = seattr[e * 3 + 2]; }
  bf16x8 afr[4];
  #pragma unroll
  for (int s = 0; s < 4; ++s) {
    int k0 = s * 32 + quad * 8;
    union { bf16x8 v; unsigned short u[8]; } af;
    #pragma unroll
    for (int j = 0; j < 8; ++j) {
      float z = ea0 * Pw[k0 + j] + ea1 * Pw[128 + k0 + j] + ea2 * Pw[256 + k0 + j]
                + Pb[k0 + j];
      af.u[j] = f2bf(z / (1.f + __expf(-z)));
    }
    afr[s] = af.v;
  }

  f32x4 acc[8];
  #pragma unroll
  for (int tt = 0; tt < 8; ++tt)
    #pragma unroll
    for (int r = 0; r < 4; ++r) acc[tt][r] = 0.f;
  #pragma unroll
  for (int tt = 0; tt < 8; ++tt)
    #pragma unroll
    for (int s = 0; s < 4; ++s) {
      bf16x8 b = *(const bf16x8*)(WeT + (tt * 16 + m) * 128 + s * 32 + quad * 8);
      acc[tt] = __builtin_amdgcn_mfma_f32_16x16x32_bf16(afr[s], b, acc[tt], 0, 0, 0);
    }

  // epilogue: C(row=quad*4+r, col=tt*16+m); gather + lrelu + att-dot + reduce
  int ebase = eb + w * 16 + quad * 4;
  int sv[4], dv[4];
  #pragma unroll
  for (int r = 0; r < 4; ++r) {
    int eg = ebase + r;
    if (eg < E) { sv[r] = ssrc[eg]; dv[r] = sdst[eg]; }
    else { sv[r] = 0; dv[r] = 0; }
  }
  #pragma unroll
  for (int h = 0; h < 4; ++h) {
    int c0 = h * 32 + m;
    int c1 = c0 + 16;
    float at0 = attw[c0], at1 = attw[c1];
    float psum[4];
    #pragma unroll
    for (int r = 0; r < 4; ++r) {
      float m0 = acc[2 * h][r]     + bf2f(xl[sv[r] * 128 + c0]) + bf2f(xr[dv[r] * 128 + c0]);
      float m1 = acc[2 * h + 1][r] + bf2f(xl[sv[r] * 128 + c1]) + bf2f(xr[dv[r] * 128 + c1]);
      m0 = (m0 > 0.f) ? m0 : 0.2f * m0;
      m1 = (m1 > 0.f) ? m1 : 0.2f * m1;
      psum[r] = m0 * at0 + m1 * at1;
    }
    #pragma unroll
    for (int o = 1; o < 16; o <<= 1) {
      #pragma unroll
      for (int r = 0; r < 4; ++r) psum[r] += __shfl_xor(psum[r], o, 16);
    }
    if (m == 0) {
      #pragma unroll
      for (int r = 0; r < 4; ++r) {
        int eg = ebase + r;
        if (eg < E) scores[eg * 4 + h] = psum[r];
      }
    }
  }
}

// ---------------- aggregation: online softmax + LN + silu + residual ----------------
__global__ __launch_bounds__(256) void aggregate_kernel(
    const unsigned short* __restrict__ xl, const float* __restrict__ scores,
    const int* __restrict__ off, const int* __restrict__ ssrc,
    const float* __restrict__ bias,
    const float* __restrict__ lng, const float* __restrict__ lnb,
    const float* __restrict__ h_in, float* __restrict__ h_out,
    unsigned short* __restrict__ hbf_out, int N) {
  int wid = threadIdx.x >> 6, lane = threadIdx.x & 63;
  int n = blockIdx.x * 4 + wid;
  if (n >= N) return;
  int hh = lane >> 4;
  int p0 = off[n], p1 = off[n + 1];
  float rm = -3.0e38f, rden = 0.f, a0 = 0.f, a1 = 0.f;
  for (int p = p0; p < p1; ++p) {
    float s = scores[p * 4 + hh];
    int sp = ssrc[p];
    float mn = fmaxf(rm, s);
    float c = __expf(rm - mn);
    float w = __expf(s - mn);
    ushort2 xv = *(const ushort2*)(xl + sp * 128 + lane * 2);
    rden = rden * c + w;
    a0 = a0 * c + w * bf2f(xv.x);
    a1 = a1 * c + w * bf2f(xv.y);
    rm = mn;
  }
  float inv = 1.f / (rden + 1e-16f);
  const float2 bb = *(const float2*)(bias + lane * 2);
  float v0 = a0 * inv + bb.x;
  float v1 = a1 * inv + bb.y;
  float s1 = v0 + v1, s2 = v0 * v0 + v1 * v1;
  #pragma unroll
  for (int o = 1; o < 64; o <<= 1) {
    s1 += __shfl_xor(s1, o, 64);
    s2 += __shfl_xor(s2, o, 64);
  }
  float mean = s1 * (1.f / 128.f);
  float var = s2 * (1.f / 128.f) - mean * mean;
  float rs = rsqrtf(var + 1e-5f);
  const float2 g2 = *(const float2*)(lng + lane * 2);
  const float2 b2 = *(const float2*)(lnb + lane * 2);
  float y0 = (v0 - mean) * rs * g2.x + b2.x;
  float y1 = (v1 - mean) * rs * g2.y + b2.y;
  float o0 = y0 / (1.f + __expf(-y0));
  float o1 = y1 / (1.f + __expf(-y1));
  if (h_in) {
    const float2 hv = *(const float2*)(h_in + n * 128 + lane * 2);
    o0 += hv.x; o1 += hv.y;
  }
  float2 ov; ov.x = o0; ov.y = o1;
  *(float2*)(h_out + n * 128 + lane * 2) = ov;
  if (hbf_out) {
    ushort2 hb; hb.x = f2bf(o0); hb.y = f2bf(o1);
    *(ushort2*)(hbf_out + n * 128 + lane * 2) = hb;
  }
}

// ---------------------------------------------------------------------------
extern "C" void kernel_launch(void* const* d_in, const int* in_sizes, int n_in,
                              void* d_out, int out_size, void* d_ws, size_t ws_size,
                              hipStream_t stream) {
  const float* x       = (const float*)d_in[0];
  const int*   eidx    = (const int*)d_in[1];
  const float* eattr   = (const float*)d_in[2];
  const float* Pw      = (const float*)d_in[3];
  const float* Pb      = (const float*)d_in[4];
  const float* l0_Wl   = (const float*)d_in[5];
  const float* l0_bl   = (const float*)d_in[6];
  const float* l0_Wr   = (const float*)d_in[7];
  const float* l0_br   = (const float*)d_in[8];
  const float* l0_We   = (const float*)d_in[9];
  const float* l0_att  = (const float*)d_in[10];
  const float* l0_bias = (const float*)d_in[11];
  const float* Wl      = (const float*)d_in[12];
  const float* bl      = (const float*)d_in[13];
  const float* Wr      = (const float*)d_in[14];
  const float* br      = (const float*)d_in[15];
  const float* We      = (const float*)d_in[16];
  const float* att     = (const float*)d_in[17];
  const float* bias    = (const float*)d_in[18];
  const float* ln_g    = (const float*)d_in[19];
  const float* ln_b    = (const float*)d_in[20];
  (void)n_in; (void)out_size; (void)ws_size;

  int N = in_sizes[0] / 12;
  int E = in_sizes[2] / 3;
  const int* srcv = eidx;
  const int* dstv = eidx + E;

  char* w = (char*)d_ws;
  unsigned short* xl_bf = (unsigned short*)w; w += (size_t)N * 128 * 2;
  unsigned short* xr_bf = (unsigned short*)w; w += (size_t)N * 128 * 2;
  unsigned short* h_bf  = (unsigned short*)w; w += (size_t)N * 128 * 2;
  float* h      = (float*)w;  w += (size_t)N * 128 * 4;
  float* scores = (float*)w;  w += (size_t)E * 4 * 4;
  float* seattr = (float*)w;  w += (size_t)E * 3 * 4;
  int* ssrc   = (int*)w;      w += (size_t)E * 4;
  int* sdst   = (int*)w;      w += (size_t)E * 4;
  int* deg    = (int*)w;      w += (size_t)N * 4;
  int* off    = (int*)w;      w += (size_t)(N + 1) * 4;
  int* cursor = (int*)w;      w += (size_t)N * 4 + 12;  // keep 16B align
  unsigned short* WeT = (unsigned short*)w; w += (size_t)4 * 16384 * 2;
  unsigned short* WlT = (unsigned short*)w; w += (size_t)3 * 16384 * 2;
  unsigned short* WrT = (unsigned short*)w; w += (size_t)3 * 16384 * 2;

  hipMemsetAsync(deg, 0, (size_t)N * 4, stream);
  int gE = (E + 255) / 256;
  count_kernel<<<gE, 256, 0, stream>>>(dstv, deg, E);
  scan_kernel<<<1, 1024, 0, stream>>>(deg, off, cursor, N);
  place_kernel<<<gE, 256, 0, stream>>>(srcv, dstv, eattr, cursor, ssrc, sdst, seattr, E);
  wt_kernel<<<10, 256, 0, stream>>>(l0_We, We, Wl, Wr, WeT, WlT, WrT);

  dim3 egrid((E + 63) / 64);
  dim3 ngrid((N + 63) / 64);
  int agrid = (N + 3) / 4;

  // layer 0 (input dim 12, no residual)
  node_proj0_kernel<<<(N * 128 + 255) / 256, 256, 0, stream>>>(
      x, l0_Wl, l0_bl, l0_Wr, l0_br, xl_bf, xr_bf, N);
  edge_score_kernel<<<egrid, 256, 0, stream>>>(
      seattr, Pw, Pb, WeT, l0_att, xl_bf, xr_bf, ssrc, sdst, scores, E);
  aggregate_kernel<<<agrid, 256, 0, stream>>>(
      xl_bf, scores, off, ssrc, l0_bias, ln_g, ln_b, nullptr, h, h_bf, N);

  // layers 1..3 (residual)
  for (int i = 0; i < 3; ++i) {
    node_proj_kernel<<<ngrid, 256, 0, stream>>>(
        h_bf, WlT + i * 16384, bl + i * 128, WrT + i * 16384, br + i * 128,
        xl_bf, xr_bf, N);
    edge_score_kernel<<<egrid, 256, 0, stream>>>(
        seattr, Pw, Pb, WeT + (i + 1) * 16384, att + i * 128,
        xl_bf, xr_bf, ssrc, sdst, scores, E);
    float* hout = (i == 2) ? (float*)d_out : h;
    unsigned short* hbfout = (i == 2) ? nullptr : h_bf;
    aggregate_kernel<<<agrid, 256, 0, stream>>>(
        xl_bf, scores, off, ssrc, bias + i * 128,
        ln_g + (i + 1) * 128, ln_b + (i + 1) * 128, h, hout, hbfout, N);
  }
}